// Round 1
// baseline (1587.656 us; speedup 1.0000x reference)
//
#include <hip/hip_runtime.h>
#include <math.h>

// Problem constants (from reference)
constexpr int E = 8, TOPK = 2, H = 1024, DFF = 2048, T = 4096; // T = B*S
constexpr int BM = 64, BN = 64, BK = 16;
constexpr int MT_MAX = T / BM;   // 64 m-tiles worst case per expert
constexpr int NT_G = DFF / BN;   // 32 n-tiles for gate/up
constexpr int NT_D = H / BN;     // 16 n-tiles for down

// ---------------- k0: zero output + counters ----------------
__global__ void k0_zero(float* __restrict__ out, int* __restrict__ cnt) {
    int i = blockIdx.x * 256 + threadIdx.x;
    int n = T * H + E;
    if (i < n) out[i] = 0.0f;
    if (blockIdx.x == 0 && threadIdx.x < E) cnt[threadIdx.x] = 0;
}

// ---------------- k1: router ----------------
// One block per token. 4 waves x 2 experts each: dot(x[t], centroid[e]).
__global__ __launch_bounds__(256) void k1_router(
    const float* __restrict__ x, const float* __restrict__ cent,
    const float* __restrict__ bias,
    int* __restrict__ cnt, int* __restrict__ token_list,
    float* __restrict__ row_w) {
    __shared__ float xs[H];
    __shared__ float aff[E];
    int t = blockIdx.x;
    const float* xr = x + (size_t)t * H;
    for (int i = threadIdx.x; i < H; i += 256) xs[i] = xr[i];
    __syncthreads();

    int wave = threadIdx.x >> 6;
    int lane = threadIdx.x & 63;
    const float* c0 = cent + (size_t)(2 * wave) * H;
    const float* c1 = cent + (size_t)(2 * wave + 1) * H;
    float a0 = 0.f, a1 = 0.f;
    for (int i = lane; i < H; i += 64) {
        float xv = xs[i];
        a0 = fmaf(xv, c0[i], a0);
        a1 = fmaf(xv, c1[i], a1);
    }
    for (int off = 32; off; off >>= 1) {
        a0 += __shfl_down(a0, off);
        a1 += __shfl_down(a1, off);
    }
    if (lane == 0) { aff[2 * wave] = a0; aff[2 * wave + 1] = a1; }
    __syncthreads();

    if (threadIdx.x == 0) {
        float s[E];
        #pragma unroll
        for (int e = 0; e < E; e++)
            s[e] = 1.0f / (1.0f + expf(-aff[e])) + bias[e];
        // top-2, jax tie-break (lowest index): strict >
        int i0 = 0;
        for (int e = 1; e < E; e++) if (s[e] > s[i0]) i0 = e;
        int i1 = -1;
        for (int e = 0; e < E; e++) {
            if (e == i0) continue;
            if (i1 < 0 || s[e] > s[i1]) i1 = e;
        }
        float m = fmaxf(s[i0], s[i1]);
        float w0 = expf(s[i0] - m), w1 = expf(s[i1] - m);
        float inv = 1.0f / (w0 + w1);
        w0 *= inv; w1 *= inv;
        int p0 = atomicAdd(&cnt[i0], 1);
        token_list[i0 * T + p0] = t; row_w[i0 * T + p0] = w0;
        int p1 = atomicAdd(&cnt[i1], 1);
        token_list[i1 * T + p1] = t; row_w[i1 * T + p1] = w1;
    }
}

// ---------------- k1.5: offsets + counts output ----------------
__global__ void k15_offsets(const int* __restrict__ cnt, int* __restrict__ off,
                            float* __restrict__ out_counts) {
    if (threadIdx.x == 0) {
        int acc = 0;
        for (int e = 0; e < E; e++) { off[e] = acc; acc += cnt[e]; }
    }
    if (threadIdx.x < E) out_counts[threadIdx.x] = (float)cnt[threadIdx.x];
}

// ---------------- k2: grouped GEMM gate+up, fused SiLU*up -> h ----------------
// g[m,n] = sum_k X[tok_m,k] * gate_w[e,n_glob,k];  same for u.  h = silu(g)*u
__global__ __launch_bounds__(256) void k2_gateup(
    const float* __restrict__ x, const float* __restrict__ gw,
    const float* __restrict__ uw,
    const int* __restrict__ cnt, const int* __restrict__ off,
    const int* __restrict__ token_list, float* __restrict__ h) {
    int bid = blockIdx.x;
    int e = bid / (MT_MAX * NT_G);
    int rem = bid % (MT_MAX * NT_G);
    int mt = rem / NT_G, nt = rem % NT_G;
    int Me = cnt[e];
    if (mt * BM >= Me) return;

    __shared__ float As[BK][BM + 4];
    __shared__ float Bg[BK][BN + 4];
    __shared__ float Bu[BK][BN + 4];
    __shared__ int toks[BM];

    int tid = threadIdx.x;
    if (tid < BM) {
        int mrow = mt * BM + tid;
        toks[tid] = (mrow < Me) ? token_list[e * T + mrow] : -1;
    }
    __syncthreads();

    const float* gwb = gw + (size_t)e * DFF * H + (size_t)(nt * BN) * H;
    const float* uwb = uw + (size_t)e * DFF * H + (size_t)(nt * BN) * H;

    int lm = tid >> 2;            // 0..63: which tile row (A) / tile col (B)
    int lk = (tid & 3) * 4;       // 0,4,8,12: k sub-offset (float4)
    int tx = tid & 15, ty = tid >> 4;

    int tok = toks[lm];
    const float* arow = (tok >= 0) ? (x + (size_t)tok * H) : x; // dummy if invalid

    float ga[4][4] = {{0}}, ua[4][4] = {{0}};

    for (int k0 = 0; k0 < H; k0 += BK) {
        float4 av = make_float4(0.f, 0.f, 0.f, 0.f);
        if (tok >= 0) av = *(const float4*)(arow + k0 + lk);
        float4 bgv = *(const float4*)(gwb + (size_t)lm * H + k0 + lk);
        float4 buv = *(const float4*)(uwb + (size_t)lm * H + k0 + lk);
        __syncthreads();
        As[lk + 0][lm] = av.x; As[lk + 1][lm] = av.y;
        As[lk + 2][lm] = av.z; As[lk + 3][lm] = av.w;
        Bg[lk + 0][lm] = bgv.x; Bg[lk + 1][lm] = bgv.y;
        Bg[lk + 2][lm] = bgv.z; Bg[lk + 3][lm] = bgv.w;
        Bu[lk + 0][lm] = buv.x; Bu[lk + 1][lm] = buv.y;
        Bu[lk + 2][lm] = buv.z; Bu[lk + 3][lm] = buv.w;
        __syncthreads();
        #pragma unroll
        for (int k = 0; k < BK; k++) {
            float4 a  = *(const float4*)&As[k][ty * 4];
            float4 bg = *(const float4*)&Bg[k][tx * 4];
            float4 bu = *(const float4*)&Bu[k][tx * 4];
            float ar[4]  = {a.x, a.y, a.z, a.w};
            float bgr[4] = {bg.x, bg.y, bg.z, bg.w};
            float bur[4] = {bu.x, bu.y, bu.z, bu.w};
            #pragma unroll
            for (int i = 0; i < 4; i++)
                #pragma unroll
                for (int j = 0; j < 4; j++) {
                    ga[i][j] = fmaf(ar[i], bgr[j], ga[i][j]);
                    ua[i][j] = fmaf(ar[i], bur[j], ua[i][j]);
                }
        }
    }

    int mbase = mt * BM;
    int offe = off[e];
    #pragma unroll
    for (int i = 0; i < 4; i++) {
        int mrow = mbase + ty * 4 + i;
        if (mrow >= Me) continue;
        size_t hrow = (size_t)(offe + mrow) * DFF + nt * BN + tx * 4;
        float4 hv;
        float g, u, sg;
        g = ga[i][0]; u = ua[i][0]; sg = 1.0f / (1.0f + expf(-g)); hv.x = g * sg * u;
        g = ga[i][1]; u = ua[i][1]; sg = 1.0f / (1.0f + expf(-g)); hv.y = g * sg * u;
        g = ga[i][2]; u = ua[i][2]; sg = 1.0f / (1.0f + expf(-g)); hv.z = g * sg * u;
        g = ga[i][3]; u = ua[i][3]; sg = 1.0f / (1.0f + expf(-g)); hv.w = g * sg * u;
        *(float4*)&h[hrow] = hv;
    }
}

// ---------------- k3: grouped GEMM down + weighted scatter-add ----------------
__global__ __launch_bounds__(256) void k3_down(
    const float* __restrict__ h, const float* __restrict__ dw,
    const int* __restrict__ cnt, const int* __restrict__ off,
    const int* __restrict__ token_list, const float* __restrict__ row_w,
    float* __restrict__ out) {
    int bid = blockIdx.x;
    int e = bid / (MT_MAX * NT_D);
    int rem = bid % (MT_MAX * NT_D);
    int mt = rem / NT_D, nt = rem % NT_D;
    int Me = cnt[e];
    if (mt * BM >= Me) return;

    __shared__ float As[BK][BM + 4];
    __shared__ float Bd[BK][BN + 4];

    int tid = threadIdx.x;
    int lm = tid >> 2;
    int lk = (tid & 3) * 4;
    int tx = tid & 15, ty = tid >> 4;

    int offe = off[e];
    bool avalid = (mt * BM + lm) < Me;
    const float* arow = h + (size_t)(offe + (avalid ? mt * BM + lm : 0)) * DFF;
    const float* dwb = dw + (size_t)e * H * DFF + (size_t)(nt * BN) * DFF;

    float acc[4][4] = {{0}};

    for (int k0 = 0; k0 < DFF; k0 += BK) {
        float4 av = make_float4(0.f, 0.f, 0.f, 0.f);
        if (avalid) av = *(const float4*)(arow + k0 + lk);
        float4 bv = *(const float4*)(dwb + (size_t)lm * DFF + k0 + lk);
        __syncthreads();
        As[lk + 0][lm] = av.x; As[lk + 1][lm] = av.y;
        As[lk + 2][lm] = av.z; As[lk + 3][lm] = av.w;
        Bd[lk + 0][lm] = bv.x; Bd[lk + 1][lm] = bv.y;
        Bd[lk + 2][lm] = bv.z; Bd[lk + 3][lm] = bv.w;
        __syncthreads();
        #pragma unroll
        for (int k = 0; k < BK; k++) {
            float4 a = *(const float4*)&As[k][ty * 4];
            float4 b = *(const float4*)&Bd[k][tx * 4];
            float ar[4] = {a.x, a.y, a.z, a.w};
            float br[4] = {b.x, b.y, b.z, b.w};
            #pragma unroll
            for (int i = 0; i < 4; i++)
                #pragma unroll
                for (int j = 0; j < 4; j++)
                    acc[i][j] = fmaf(ar[i], br[j], acc[i][j]);
        }
    }

    int mbase = mt * BM;
    #pragma unroll
    for (int i = 0; i < 4; i++) {
        int mrow = mbase + ty * 4 + i;
        if (mrow >= Me) continue;
        int tok = token_list[e * T + mrow];
        float w = row_w[e * T + mrow];
        size_t obase = (size_t)tok * H + nt * BN + tx * 4;
        #pragma unroll
        for (int j = 0; j < 4; j++)
            atomicAdd(&out[obase + j], w * acc[i][j]);
    }
}

// ---------------- launch ----------------
extern "C" void kernel_launch(void* const* d_in, const int* in_sizes, int n_in,
                              void* d_out, int out_size, void* d_ws, size_t ws_size,
                              hipStream_t stream) {
    const float* x     = (const float*)d_in[0];
    const float* cent  = (const float*)d_in[1];
    const float* gw    = (const float*)d_in[2];
    const float* uw    = (const float*)d_in[3];
    const float* dw    = (const float*)d_in[4];
    const float* bias  = (const float*)d_in[5];
    float* out = (float*)d_out;

    // workspace layout
    char* ws = (char*)d_ws;
    int* cnt = (int*)ws;                                  // E ints
    int* off = cnt + E;                                   // E ints
    int* token_list = (int*)(ws + 64);                    // E*T ints   (128 KB)
    float* row_w = (float*)(ws + 64 + (size_t)E * T * 4); // E*T floats (128 KB)
    size_t hoff = ((64 + (size_t)E * T * 8) + 255) & ~(size_t)255;
    float* h = (float*)(ws + hoff);                       // 8192*2048 floats (64 MB)

    int nz = T * H + E;
    k0_zero<<<(nz + 255) / 256, 256, 0, stream>>>(out, cnt);
    k1_router<<<T, 256, 0, stream>>>(x, cent, bias, cnt, token_list, row_w);
    k15_offsets<<<1, 64, 0, stream>>>(cnt, off, out + (size_t)T * H);
    k2_gateup<<<E * MT_MAX * NT_G, 256, 0, stream>>>(x, gw, uw, cnt, off, token_list, h);
    k3_down<<<E * MT_MAX * NT_D, 256, 0, stream>>>(h, dw, cnt, off, token_list, row_w, out);
}

// Round 2
// 489.000 us; speedup vs baseline: 3.2467x; 3.2467x over previous
//
#include <hip/hip_runtime.h>
#include <math.h>

// Problem constants
constexpr int E = 8, H = 1024, DFF = 2048, T = 4096;
constexpr int TR = 8192;          // total routed rows = T * topk
constexpr int BK = 32;            // K-tile (bf16)

typedef __bf16 bf16x8 __attribute__((ext_vector_type(8)));
typedef __bf16 bf16x4 __attribute__((ext_vector_type(4)));
typedef float f32x4 __attribute__((ext_vector_type(4)));

__device__ __forceinline__ void gload16(const void* g, void* l) {
    __builtin_amdgcn_global_load_lds(
        (const __attribute__((address_space(1))) unsigned int*)g,
        (__attribute__((address_space(3))) unsigned int*)l, 16, 0, 0);
}

// ---------------- k0: zero expert counters ----------------
__global__ void k0_init(int* __restrict__ cnt) {
    if (threadIdx.x < E) cnt[threadIdx.x] = 0;
}

// ---------------- k1: router (fp32, unchanged math from round 1) ----------------
__global__ __launch_bounds__(256) void k1_router(
    const float* __restrict__ x, const float* __restrict__ cent,
    const float* __restrict__ bias,
    int* __restrict__ cnt, int* __restrict__ token_list,
    int* __restrict__ se, int* __restrict__ sp, float* __restrict__ sw) {
    __shared__ float xs[H];
    __shared__ float aff[E];
    int t = blockIdx.x;
    const float* xr = x + (size_t)t * H;
    for (int i = threadIdx.x; i < H; i += 256) xs[i] = xr[i];
    __syncthreads();

    int wave = threadIdx.x >> 6;
    int lane = threadIdx.x & 63;
    const float* c0 = cent + (size_t)(2 * wave) * H;
    const float* c1 = cent + (size_t)(2 * wave + 1) * H;
    float a0 = 0.f, a1 = 0.f;
    for (int i = lane; i < H; i += 64) {
        float xv = xs[i];
        a0 = fmaf(xv, c0[i], a0);
        a1 = fmaf(xv, c1[i], a1);
    }
    for (int off = 32; off; off >>= 1) {
        a0 += __shfl_down(a0, off);
        a1 += __shfl_down(a1, off);
    }
    if (lane == 0) { aff[2 * wave] = a0; aff[2 * wave + 1] = a1; }
    __syncthreads();

    if (threadIdx.x == 0) {
        float s[E];
        #pragma unroll
        for (int e = 0; e < E; e++)
            s[e] = 1.0f / (1.0f + expf(-aff[e])) + bias[e];
        int i0 = 0;
        for (int e = 1; e < E; e++) if (s[e] > s[i0]) i0 = e;
        int i1 = -1;
        for (int e = 0; e < E; e++) {
            if (e == i0) continue;
            if (i1 < 0 || s[e] > s[i1]) i1 = e;
        }
        float m = fmaxf(s[i0], s[i1]);
        float w0 = expf(s[i0] - m), w1 = expf(s[i1] - m);
        float inv = 1.0f / (w0 + w1);
        w0 *= inv; w1 *= inv;
        int p0 = atomicAdd(&cnt[i0], 1);
        int p1 = atomicAdd(&cnt[i1], 1);
        token_list[i0 * T + p0] = t;
        token_list[i1 * T + p1] = t;
        se[2 * t] = i0; sp[2 * t] = p0; sw[2 * t] = w0;
        se[2 * t + 1] = i1; sp[2 * t + 1] = p1; sw[2 * t + 1] = w1;
    }
}

// ---------------- k1.5: offsets + counts output ----------------
__global__ void k15_offsets(const int* __restrict__ cnt, int* __restrict__ off,
                            float* __restrict__ out_counts) {
    if (threadIdx.x == 0) {
        int acc = 0;
        for (int e = 0; e < E; e++) { off[e] = acc; acc += cnt[e]; }
    }
    if (threadIdx.x < E) out_counts[threadIdx.x] = (float)cnt[threadIdx.x];
}

// ---------------- conv: fp32 -> bf16, vectorized ----------------
__global__ __launch_bounds__(256) void k_conv(const float* __restrict__ in,
                                              __bf16* __restrict__ out, int n4) {
    int i = blockIdx.x * 256 + threadIdx.x;
    if (i < n4) {
        float4 v = ((const float4*)in)[i];
        bf16x4 o = {(__bf16)v.x, (__bf16)v.y, (__bf16)v.z, (__bf16)v.w};
        ((bf16x4*)out)[i] = o;
    }
}

// ---------------- permute: gather selected token rows -> xp (bf16) ----------------
__global__ __launch_bounds__(256) void k_permute(
    const float* __restrict__ x, const int* __restrict__ token_list,
    const int* __restrict__ cnt, const int* __restrict__ off,
    __bf16* __restrict__ xp) {
    int e = blockIdx.y;
    int Me = cnt[e];
    int rid = threadIdx.x >> 6;
    int lane = threadIdx.x & 63;
    int p = blockIdx.x * 4 + rid;
    if (p >= Me) return;
    int tok = token_list[e * T + p];
    const float4* src = (const float4*)(x + (size_t)tok * H);
    bf16x4* dst = (bf16x4*)(xp + (size_t)(off[e] + p) * H);
    #pragma unroll
    for (int it = 0; it < 4; it++) {
        float4 v = src[lane + it * 64];
        bf16x4 o = {(__bf16)v.x, (__bf16)v.y, (__bf16)v.z, (__bf16)v.w};
        dst[lane + it * 64] = o;
    }
}

// ---------------- k2: grouped GEMM gate+up (MFMA), fused SiLU*up -> h ----------------
// Tile: 128 (m) x 64 (n) per block, both gate and up. 4 waves, each 64x32.
__global__ __launch_bounds__(256) void k2_gateup(
    const __bf16* __restrict__ xp, const __bf16* __restrict__ gwb,
    const __bf16* __restrict__ uwb, const int* __restrict__ cnt,
    const int* __restrict__ off, __bf16* __restrict__ h) {
    int bid = blockIdx.x;
    int e = bid >> 10;            // 32 mt * 32 nt
    int rem = bid & 1023;
    int mt = rem >> 5;            // 0..31
    int nt = rem & 31;            // 0..31  (DFF/64)
    int Me = cnt[e];
    if (mt * 128 >= Me) return;
    int offe = off[e];

    __shared__ __bf16 As[128 * 32];
    __shared__ __bf16 Bg[64 * 32];
    __shared__ __bf16 Bu[64 * 32];

    int tid = threadIdx.x;
    int lane = tid & 63, w = tid >> 6;
    int wm = w >> 1, wn = w & 1;

    // staging source addresses (swizzled k-slot)
    int l0 = tid, l1 = 256 + tid;
    int ar0 = l0 >> 2, akq0 = (l0 & 3) ^ ((ar0 >> 1) & 3);
    int ar1 = l1 >> 2, akq1 = (l1 & 3) ^ ((ar1 >> 1) & 3);
    int arow_g0 = offe + mt * 128 + ar0; if (arow_g0 > TR - 1) arow_g0 = TR - 1;
    int arow_g1 = offe + mt * 128 + ar1; if (arow_g1 > TR - 1) arow_g1 = TR - 1;
    const __bf16* asrc0 = xp + (size_t)arow_g0 * H + akq0 * 8;
    const __bf16* asrc1 = xp + (size_t)arow_g1 * H + akq1 * 8;
    const __bf16* gsrc = gwb + ((size_t)e * DFF + nt * 64 + ar0) * H + akq0 * 8;
    const __bf16* usrc = uwb + ((size_t)e * DFF + nt * 64 + ar0) * H + akq0 * 8;

    f32x4 accg[4][2] = {};
    f32x4 accu[4][2] = {};

    int kq = lane >> 4;
    int m15 = lane & 15;

    for (int k0 = 0; k0 < H; k0 += BK) {
        gload16(asrc0 + k0, &As[l0 * 8]);
        gload16(asrc1 + k0, &As[l1 * 8]);
        gload16(gsrc + k0, &Bg[tid * 8]);
        gload16(usrc + k0, &Bu[tid * 8]);
        __syncthreads();

        bf16x8 af[4], gf[2], uf[2];
        #pragma unroll
        for (int i = 0; i < 4; i++) {
            int row = wm * 64 + i * 16 + m15;
            int slot = kq ^ ((row >> 1) & 3);
            af[i] = *(const bf16x8*)&As[row * 32 + slot * 8];
        }
        #pragma unroll
        for (int j = 0; j < 2; j++) {
            int row = wn * 32 + j * 16 + m15;
            int slot = kq ^ ((row >> 1) & 3);
            gf[j] = *(const bf16x8*)&Bg[row * 32 + slot * 8];
            uf[j] = *(const bf16x8*)&Bu[row * 32 + slot * 8];
        }
        #pragma unroll
        for (int i = 0; i < 4; i++)
            #pragma unroll
            for (int j = 0; j < 2; j++) {
                accg[i][j] = __builtin_amdgcn_mfma_f32_16x16x32_bf16(af[i], gf[j], accg[i][j], 0, 0, 0);
                accu[i][j] = __builtin_amdgcn_mfma_f32_16x16x32_bf16(af[i], uf[j], accu[i][j], 0, 0, 0);
            }
        __syncthreads();
    }

    // epilogue: h = silu(g) * u, bf16
    #pragma unroll
    for (int i = 0; i < 4; i++)
        #pragma unroll
        for (int j = 0; j < 2; j++) {
            int nloc = wn * 32 + j * 16 + m15;
            size_t c = (size_t)nt * 64 + nloc;
            #pragma unroll
            for (int p = 0; p < 4; p++) {
                int mloc = wm * 64 + i * 16 + kq * 4 + p;
                int mrow = mt * 128 + mloc;
                if (mrow < Me) {
                    float g = accg[i][j][p], u = accu[i][j][p];
                    float sig = 1.0f / (1.0f + __expf(-g));
                    h[(size_t)(offe + mrow) * DFF + c] = (__bf16)(g * sig * u);
                }
            }
        }
}

// ---------------- k3: grouped GEMM down (MFMA) -> per-row y (bf16) ----------------
// Tile: 128 (m) x 128 (n) per block. 4 waves 2x2, each 64x64.
__global__ __launch_bounds__(256) void k3_down(
    const __bf16* __restrict__ h, const __bf16* __restrict__ dwb,
    const int* __restrict__ cnt, const int* __restrict__ off,
    __bf16* __restrict__ y) {
    int bid = blockIdx.x;
    int e = bid >> 8;             // 32 mt * 8 nt
    int rem = bid & 255;
    int mt = rem >> 3;            // 0..31
    int nt = rem & 7;             // 0..7  (H/128)
    int Me = cnt[e];
    if (mt * 128 >= Me) return;
    int offe = off[e];

    __shared__ __bf16 As[128 * 32];
    __shared__ __bf16 Bs[128 * 32];

    int tid = threadIdx.x;
    int lane = tid & 63, w = tid >> 6;
    int wm = w >> 1, wn = w & 1;

    int l0 = tid, l1 = 256 + tid;
    int r0 = l0 >> 2, kq0 = (l0 & 3) ^ ((r0 >> 1) & 3);
    int r1 = l1 >> 2, kq1 = (l1 & 3) ^ ((r1 >> 1) & 3);
    int arow_g0 = offe + mt * 128 + r0; if (arow_g0 > TR - 1) arow_g0 = TR - 1;
    int arow_g1 = offe + mt * 128 + r1; if (arow_g1 > TR - 1) arow_g1 = TR - 1;
    const __bf16* asrc0 = h + (size_t)arow_g0 * DFF + kq0 * 8;
    const __bf16* asrc1 = h + (size_t)arow_g1 * DFF + kq1 * 8;
    const __bf16* bsrc0 = dwb + ((size_t)e * H + nt * 128 + r0) * DFF + kq0 * 8;
    const __bf16* bsrc1 = dwb + ((size_t)e * H + nt * 128 + r1) * DFF + kq1 * 8;

    f32x4 acc[4][4] = {};
    int kq = lane >> 4;
    int m15 = lane & 15;

    for (int k0 = 0; k0 < DFF; k0 += BK) {
        gload16(asrc0 + k0, &As[l0 * 8]);
        gload16(asrc1 + k0, &As[l1 * 8]);
        gload16(bsrc0 + k0, &Bs[l0 * 8]);
        gload16(bsrc1 + k0, &Bs[l1 * 8]);
        __syncthreads();

        bf16x8 af[4], bf[4];
        #pragma unroll
        for (int i = 0; i < 4; i++) {
            int row = wm * 64 + i * 16 + m15;
            int slot = kq ^ ((row >> 1) & 3);
            af[i] = *(const bf16x8*)&As[row * 32 + slot * 8];
        }
        #pragma unroll
        for (int j = 0; j < 4; j++) {
            int row = wn * 64 + j * 16 + m15;
            int slot = kq ^ ((row >> 1) & 3);
            bf[j] = *(const bf16x8*)&Bs[row * 32 + slot * 8];
        }
        #pragma unroll
        for (int i = 0; i < 4; i++)
            #pragma unroll
            for (int j = 0; j < 4; j++)
                acc[i][j] = __builtin_amdgcn_mfma_f32_16x16x32_bf16(af[i], bf[j], acc[i][j], 0, 0, 0);
        __syncthreads();
    }

    #pragma unroll
    for (int i = 0; i < 4; i++)
        #pragma unroll
        for (int j = 0; j < 4; j++) {
            int nglob = nt * 128 + wn * 64 + j * 16 + m15;
            #pragma unroll
            for (int p = 0; p < 4; p++) {
                int mloc = wm * 64 + i * 16 + kq * 4 + p;
                int mrow = mt * 128 + mloc;
                if (mrow < Me)
                    y[(size_t)(offe + mrow) * H + nglob] = (__bf16)acc[i][j][p];
            }
        }
}

// ---------------- gather: weighted top-2 combine -> out ----------------
__global__ __launch_bounds__(256) void k_gather(
    const __bf16* __restrict__ y, const int* __restrict__ se,
    const int* __restrict__ sp, const float* __restrict__ sw,
    const int* __restrict__ off, float* __restrict__ out) {
    int t = blockIdx.x;
    int r0 = off[se[2 * t]] + sp[2 * t];
    int r1 = off[se[2 * t + 1]] + sp[2 * t + 1];
    float w0 = sw[2 * t], w1 = sw[2 * t + 1];
    const bf16x4* y0 = (const bf16x4*)(y + (size_t)r0 * H);
    const bf16x4* y1 = (const bf16x4*)(y + (size_t)r1 * H);
    float4* o = (float4*)(out + (size_t)t * H);
    int c = threadIdx.x;  // 256 threads x 4 floats = 1024
    bf16x4 a = y0[c], b = y1[c];
    float4 v;
    v.x = w0 * (float)a[0] + w1 * (float)b[0];
    v.y = w0 * (float)a[1] + w1 * (float)b[1];
    v.z = w0 * (float)a[2] + w1 * (float)b[2];
    v.w = w0 * (float)a[3] + w1 * (float)b[3];
    o[c] = v;
}

// ---------------- launch ----------------
extern "C" void kernel_launch(void* const* d_in, const int* in_sizes, int n_in,
                              void* d_out, int out_size, void* d_ws, size_t ws_size,
                              hipStream_t stream) {
    const float* x    = (const float*)d_in[0];
    const float* cent = (const float*)d_in[1];
    const float* gw   = (const float*)d_in[2];
    const float* uw   = (const float*)d_in[3];
    const float* dw   = (const float*)d_in[4];
    const float* bias = (const float*)d_in[5];
    float* out = (float*)d_out;

    // workspace layout (bytes)
    char* ws = (char*)d_ws;
    int*   cnt        = (int*)(ws + 0);          // 8
    int*   off        = (int*)(ws + 64);         // 8
    int*   se         = (int*)(ws + 128);                      // 2T
    int*   sp         = (int*)(ws + 128 + 32768);              // 2T
    float* sw         = (float*)(ws + 128 + 65536);            // 2T
    int*   token_list = (int*)(ws + 128 + 98304);              // E*T (128 KB)
    const size_t MB = 1u << 20;
    __bf16* gwb = (__bf16*)(ws + 1 * MB);                  // 32 MB (E*DFF*H bf16)
    __bf16* uwb = (__bf16*)(ws + 1 * MB + 33554432);       // 32 MB
    __bf16* dwb = gwb;                                     // alias: used after k2
    __bf16* xp  = (__bf16*)(ws + 1 * MB + 67108864);       // 16 MB (TR*H bf16)
    __bf16* y   = xp;                                      // alias: used after k2
    __bf16* h   = (__bf16*)(ws + 1 * MB + 83886080);       // 32 MB (TR*DFF bf16)

    const int W4 = E * DFF * H / 4;  // float4 count per weight tensor

    k0_init<<<1, 64, 0, stream>>>(cnt);
    k_conv<<<(W4 + 255) / 256, 256, 0, stream>>>(gw, gwb, W4);
    k_conv<<<(W4 + 255) / 256, 256, 0, stream>>>(uw, uwb, W4);
    k1_router<<<T, 256, 0, stream>>>(x, cent, bias, cnt, token_list, se, sp, sw);
    k15_offsets<<<1, 64, 0, stream>>>(cnt, off, out + (size_t)T * H);
    k_permute<<<dim3(T / 4, E), 256, 0, stream>>>(x, token_list, cnt, off, xp);
    k2_gateup<<<E * 32 * 32, 256, 0, stream>>>(xp, gwb, uwb, cnt, off, h);
    k_conv<<<(W4 + 255) / 256, 256, 0, stream>>>(dw, dwb, W4);  // aliases gwb; after k2
    k3_down<<<E * 32 * 8, 256, 0, stream>>>(h, dwb, cnt, off, y);  // y aliases xp; after k2
    k_gather<<<T, 256, 0, stream>>>(y, se, sp, sw, off, out);
}

// Round 3
// 440.361 us; speedup vs baseline: 3.6054x; 1.1105x over previous
//
#include <hip/hip_runtime.h>
#include <math.h>

// Problem constants
constexpr int E = 8, H = 1024, DFF = 2048, T = 4096;
constexpr int TR = 8192;          // total routed rows = T * topk
constexpr int BK = 32;            // K-tile (bf16)

typedef __bf16 bf16x8 __attribute__((ext_vector_type(8)));
typedef __bf16 bf16x4 __attribute__((ext_vector_type(4)));
typedef float f32x4 __attribute__((ext_vector_type(4)));

__device__ __forceinline__ void gload16(const void* g, void* l) {
    __builtin_amdgcn_global_load_lds(
        (const __attribute__((address_space(1))) unsigned int*)g,
        (__attribute__((address_space(3))) unsigned int*)l, 16, 0, 0);
}

// ---------------- k1: affinity + top-2 (atomic-free) ----------------
// 4 tokens per block (one per wave). Centroids staged in LDS (32 KB).
__global__ __launch_bounds__(256) void k1_affinity(
    const float* __restrict__ x, const float* __restrict__ cent,
    const float* __restrict__ bias,
    int* __restrict__ se, float* __restrict__ sw) {
    __shared__ float cs[E * H];
    int tid = threadIdx.x;
    for (int i = tid; i < E * H / 4; i += 256)
        ((float4*)cs)[i] = ((const float4*)cent)[i];
    __syncthreads();

    int wave = tid >> 6, lane = tid & 63;
    int t = blockIdx.x * 4 + wave;
    const float4* xr = (const float4*)(x + (size_t)t * H);
    float acc[E] = {};
    #pragma unroll
    for (int it = 0; it < 4; it++) {
        float4 xv = xr[lane + it * 64];
        #pragma unroll
        for (int e = 0; e < E; e++) {
            float4 cv = ((const float4*)(cs + e * H))[lane + it * 64];
            acc[e] = fmaf(xv.x, cv.x, acc[e]);
            acc[e] = fmaf(xv.y, cv.y, acc[e]);
            acc[e] = fmaf(xv.z, cv.z, acc[e]);
            acc[e] = fmaf(xv.w, cv.w, acc[e]);
        }
    }
    #pragma unroll
    for (int off = 32; off; off >>= 1)
        #pragma unroll
        for (int e = 0; e < E; e++) acc[e] += __shfl_down(acc[e], off);

    if (lane == 0) {
        float s[E];
        #pragma unroll
        for (int e = 0; e < E; e++)
            s[e] = 1.0f / (1.0f + expf(-acc[e])) + bias[e];
        int i0 = 0;
        for (int e = 1; e < E; e++) if (s[e] > s[i0]) i0 = e;
        int i1 = -1;
        for (int e = 0; e < E; e++) {
            if (e == i0) continue;
            if (i1 < 0 || s[e] > s[i1]) i1 = e;
        }
        float m = fmaxf(s[i0], s[i1]);
        float w0 = expf(s[i0] - m), w1 = expf(s[i1] - m);
        float inv = 1.0f / (w0 + w1);
        se[2 * t] = i0;     sw[2 * t] = w0 * inv;
        se[2 * t + 1] = i1; sw[2 * t + 1] = w1 * inv;
    }
}

// ---------------- k1b: per-expert partition via block scan ----------------
// One block per expert; stable ascending order over the 2T (token,slot) entries.
__global__ __launch_bounds__(256) void k1b_partition(
    const int* __restrict__ se, int* __restrict__ token_list,
    int* __restrict__ sp, int* __restrict__ cnt) {
    int e = blockIdx.x;
    int tid = threadIdx.x;
    int wave = tid >> 6, lane = tid & 63;
    __shared__ int wsum[4];
    int running = 0;
    for (int c0 = 0; c0 < 2 * T; c0 += 256) {
        int i = c0 + tid;
        bool pred = (se[i] == e);
        unsigned long long mask = __ballot(pred);
        int pos_in_wave = __popcll(mask & ((1ull << lane) - 1ull));
        if (lane == 0) wsum[wave] = __popcll(mask);
        __syncthreads();
        int wbase = 0;
        for (int w2 = 0; w2 < wave; w2++) wbase += wsum[w2];
        int total = wsum[0] + wsum[1] + wsum[2] + wsum[3];
        if (pred) {
            int p = running + wbase + pos_in_wave;
            token_list[e * T + p] = i >> 1;
            sp[i] = p;
        }
        running += total;
        __syncthreads();
    }
    if (tid == 0) cnt[e] = running;
}

// ---------------- k1.5: offsets + counts output ----------------
__global__ void k15_offsets(const int* __restrict__ cnt, int* __restrict__ off,
                            float* __restrict__ out_counts) {
    if (threadIdx.x == 0) {
        int acc = 0;
        for (int e = 0; e < E; e++) { off[e] = acc; acc += cnt[e]; }
    }
    if (threadIdx.x < E) out_counts[threadIdx.x] = (float)cnt[threadIdx.x];
}

// ---------------- conv: fp32 -> bf16, vectorized ----------------
__global__ __launch_bounds__(256) void k_conv(const float* __restrict__ in,
                                              __bf16* __restrict__ out, int n4) {
    int i = blockIdx.x * 256 + threadIdx.x;
    if (i < n4) {
        float4 v = ((const float4*)in)[i];
        bf16x4 o = {(__bf16)v.x, (__bf16)v.y, (__bf16)v.z, (__bf16)v.w};
        ((bf16x4*)out)[i] = o;
    }
}

// ---------------- k2: grouped GEMM gate+up (MFMA), fused SiLU*up -> h ----------------
// Tile: 128 (m) x 64 (n) per block. A-rows gathered via token_list indirection.
__global__ __launch_bounds__(256) void k2_gateup(
    const __bf16* __restrict__ xb, const __bf16* __restrict__ gwb,
    const __bf16* __restrict__ uwb, const int* __restrict__ cnt,
    const int* __restrict__ off, const int* __restrict__ token_list,
    __bf16* __restrict__ h) {
    int bid = blockIdx.x;
    int e = bid >> 10;            // 32 mt * 32 nt
    int rem = bid & 1023;
    int mt = rem >> 5;            // 0..31
    int nt = rem & 31;            // 0..31  (DFF/64)
    int Me = cnt[e];
    if (mt * 128 >= Me) return;
    int offe = off[e];

    __shared__ __bf16 As[128 * 32];
    __shared__ __bf16 Bg[64 * 32];
    __shared__ __bf16 Bu[64 * 32];

    int tid = threadIdx.x;
    int lane = tid & 63, w = tid >> 6;
    int wm = w >> 1, wn = w & 1;

    // staging source addresses (swizzled k-slot); A via token gather
    int l0 = tid, l1 = 256 + tid;
    int ar0 = l0 >> 2, akq0 = (l0 & 3) ^ ((ar0 >> 1) & 3);
    int ar1 = l1 >> 2, akq1 = (l1 & 3) ^ ((ar1 >> 1) & 3);
    int row0 = mt * 128 + ar0; if (row0 >= Me) row0 = Me - 1;
    int row1 = mt * 128 + ar1; if (row1 >= Me) row1 = Me - 1;
    int tok0 = token_list[e * T + row0];
    int tok1 = token_list[e * T + row1];
    const __bf16* asrc0 = xb + (size_t)tok0 * H + akq0 * 8;
    const __bf16* asrc1 = xb + (size_t)tok1 * H + akq1 * 8;
    const __bf16* gsrc = gwb + ((size_t)e * DFF + nt * 64 + ar0) * H + akq0 * 8;
    const __bf16* usrc = uwb + ((size_t)e * DFF + nt * 64 + ar0) * H + akq0 * 8;

    f32x4 accg[4][2] = {};
    f32x4 accu[4][2] = {};

    int kq = lane >> 4;
    int m15 = lane & 15;

    for (int k0 = 0; k0 < H; k0 += BK) {
        gload16(asrc0 + k0, &As[l0 * 8]);
        gload16(asrc1 + k0, &As[l1 * 8]);
        gload16(gsrc + k0, &Bg[tid * 8]);
        gload16(usrc + k0, &Bu[tid * 8]);
        __syncthreads();

        bf16x8 af[4], gf[2], uf[2];
        #pragma unroll
        for (int i = 0; i < 4; i++) {
            int row = wm * 64 + i * 16 + m15;
            int slot = kq ^ ((row >> 1) & 3);
            af[i] = *(const bf16x8*)&As[row * 32 + slot * 8];
        }
        #pragma unroll
        for (int j = 0; j < 2; j++) {
            int row = wn * 32 + j * 16 + m15;
            int slot = kq ^ ((row >> 1) & 3);
            gf[j] = *(const bf16x8*)&Bg[row * 32 + slot * 8];
            uf[j] = *(const bf16x8*)&Bu[row * 32 + slot * 8];
        }
        #pragma unroll
        for (int i = 0; i < 4; i++)
            #pragma unroll
            for (int j = 0; j < 2; j++) {
                accg[i][j] = __builtin_amdgcn_mfma_f32_16x16x32_bf16(af[i], gf[j], accg[i][j], 0, 0, 0);
                accu[i][j] = __builtin_amdgcn_mfma_f32_16x16x32_bf16(af[i], uf[j], accu[i][j], 0, 0, 0);
            }
        __syncthreads();
    }

    // epilogue: h = silu(g) * u, bf16
    #pragma unroll
    for (int i = 0; i < 4; i++)
        #pragma unroll
        for (int j = 0; j < 2; j++) {
            int nloc = wn * 32 + j * 16 + m15;
            size_t c = (size_t)nt * 64 + nloc;
            #pragma unroll
            for (int p = 0; p < 4; p++) {
                int mloc = wm * 64 + i * 16 + kq * 4 + p;
                int mrow = mt * 128 + mloc;
                if (mrow < Me) {
                    float g = accg[i][j][p], u = accu[i][j][p];
                    float sig = 1.0f / (1.0f + __expf(-g));
                    h[(size_t)(offe + mrow) * DFF + c] = (__bf16)(g * sig * u);
                }
            }
        }
}

// ---------------- k3: grouped GEMM down (MFMA) -> per-row y (bf16) ----------------
__global__ __launch_bounds__(256) void k3_down(
    const __bf16* __restrict__ h, const __bf16* __restrict__ dwb,
    const int* __restrict__ cnt, const int* __restrict__ off,
    __bf16* __restrict__ y) {
    int bid = blockIdx.x;
    int e = bid >> 8;             // 32 mt * 8 nt
    int rem = bid & 255;
    int mt = rem >> 3;            // 0..31
    int nt = rem & 7;             // 0..7  (H/128)
    int Me = cnt[e];
    if (mt * 128 >= Me) return;
    int offe = off[e];

    __shared__ __bf16 As[128 * 32];
    __shared__ __bf16 Bs[128 * 32];

    int tid = threadIdx.x;
    int lane = tid & 63, w = tid >> 6;
    int wm = w >> 1, wn = w & 1;

    int l0 = tid, l1 = 256 + tid;
    int r0 = l0 >> 2, kq0 = (l0 & 3) ^ ((r0 >> 1) & 3);
    int r1 = l1 >> 2, kq1 = (l1 & 3) ^ ((r1 >> 1) & 3);
    int arow_g0 = offe + mt * 128 + r0; if (arow_g0 > TR - 1) arow_g0 = TR - 1;
    int arow_g1 = offe + mt * 128 + r1; if (arow_g1 > TR - 1) arow_g1 = TR - 1;
    const __bf16* asrc0 = h + (size_t)arow_g0 * DFF + kq0 * 8;
    const __bf16* asrc1 = h + (size_t)arow_g1 * DFF + kq1 * 8;
    const __bf16* bsrc0 = dwb + ((size_t)e * H + nt * 128 + r0) * DFF + kq0 * 8;
    const __bf16* bsrc1 = dwb + ((size_t)e * H + nt * 128 + r1) * DFF + kq1 * 8;

    f32x4 acc[4][4] = {};
    int kq = lane >> 4;
    int m15 = lane & 15;

    for (int k0 = 0; k0 < DFF; k0 += BK) {
        gload16(asrc0 + k0, &As[l0 * 8]);
        gload16(asrc1 + k0, &As[l1 * 8]);
        gload16(bsrc0 + k0, &Bs[l0 * 8]);
        gload16(bsrc1 + k0, &Bs[l1 * 8]);
        __syncthreads();

        bf16x8 af[4], bf[4];
        #pragma unroll
        for (int i = 0; i < 4; i++) {
            int row = wm * 64 + i * 16 + m15;
            int slot = kq ^ ((row >> 1) & 3);
            af[i] = *(const bf16x8*)&As[row * 32 + slot * 8];
        }
        #pragma unroll
        for (int j = 0; j < 4; j++) {
            int row = wn * 64 + j * 16 + m15;
            int slot = kq ^ ((row >> 1) & 3);
            bf[j] = *(const bf16x8*)&Bs[row * 32 + slot * 8];
        }
        #pragma unroll
        for (int i = 0; i < 4; i++)
            #pragma unroll
            for (int j = 0; j < 4; j++)
                acc[i][j] = __builtin_amdgcn_mfma_f32_16x16x32_bf16(af[i], bf[j], acc[i][j], 0, 0, 0);
        __syncthreads();
    }

    #pragma unroll
    for (int i = 0; i < 4; i++)
        #pragma unroll
        for (int j = 0; j < 4; j++) {
            int nglob = nt * 128 + wn * 64 + j * 16 + m15;
            #pragma unroll
            for (int p = 0; p < 4; p++) {
                int mloc = wm * 64 + i * 16 + kq * 4 + p;
                int mrow = mt * 128 + mloc;
                if (mrow < Me)
                    y[(size_t)(offe + mrow) * H + nglob] = (__bf16)acc[i][j][p];
            }
        }
}

// ---------------- gather: weighted top-2 combine -> out ----------------
__global__ __launch_bounds__(256) void k_gather(
    const __bf16* __restrict__ y, const int* __restrict__ se,
    const int* __restrict__ sp, const float* __restrict__ sw,
    const int* __restrict__ off, float* __restrict__ out) {
    int t = blockIdx.x;
    int r0 = off[se[2 * t]] + sp[2 * t];
    int r1 = off[se[2 * t + 1]] + sp[2 * t + 1];
    float w0 = sw[2 * t], w1 = sw[2 * t + 1];
    const bf16x4* y0 = (const bf16x4*)(y + (size_t)r0 * H);
    const bf16x4* y1 = (const bf16x4*)(y + (size_t)r1 * H);
    float4* o = (float4*)(out + (size_t)t * H);
    int c = threadIdx.x;  // 256 threads x 4 floats = 1024
    bf16x4 a = y0[c], b = y1[c];
    float4 v;
    v.x = w0 * (float)a[0] + w1 * (float)b[0];
    v.y = w0 * (float)a[1] + w1 * (float)b[1];
    v.z = w0 * (float)a[2] + w1 * (float)b[2];
    v.w = w0 * (float)a[3] + w1 * (float)b[3];
    o[c] = v;
}

// ---------------- launch ----------------
extern "C" void kernel_launch(void* const* d_in, const int* in_sizes, int n_in,
                              void* d_out, int out_size, void* d_ws, size_t ws_size,
                              hipStream_t stream) {
    const float* x    = (const float*)d_in[0];
    const float* cent = (const float*)d_in[1];
    const float* gw   = (const float*)d_in[2];
    const float* uw   = (const float*)d_in[3];
    const float* dw   = (const float*)d_in[4];
    const float* bias = (const float*)d_in[5];
    float* out = (float*)d_out;

    // workspace layout (bytes)
    char* ws = (char*)d_ws;
    int*   cnt        = (int*)(ws + 0);                        // 8 ints
    int*   off        = (int*)(ws + 64);                       // 8 ints
    int*   se         = (int*)(ws + 128);                      // 2T ints (32 KB)
    int*   sp         = (int*)(ws + 128 + 32768);              // 2T ints
    float* sw         = (float*)(ws + 128 + 65536);            // 2T floats
    int*   token_list = (int*)(ws + 128 + 98304);              // E*T (128 KB)
    const size_t MB = 1u << 20;
    __bf16* gwb = (__bf16*)(ws + 1 * MB);                  // 32 MB (E*DFF*H)
    __bf16* uwb = (__bf16*)(ws + 1 * MB + 33554432);       // 32 MB
    __bf16* dwb = gwb;                                     // alias: after k2
    __bf16* y   = uwb;                                     // alias: uwb dead after k2
    __bf16* xb  = (__bf16*)(ws + 1 * MB + 67108864);       // 8 MB (T*H)
    __bf16* h   = (__bf16*)(ws + 1 * MB + 75497472);       // 32 MB (TR*DFF)

    const int W4 = E * DFF * H / 4;  // float4 count per weight tensor
    const int X4 = T * H / 4;

    k_conv<<<(W4 + 255) / 256, 256, 0, stream>>>(gw, gwb, W4);
    k_conv<<<(W4 + 255) / 256, 256, 0, stream>>>(uw, uwb, W4);
    k_conv<<<(X4 + 255) / 256, 256, 0, stream>>>(x, xb, X4);
    k1_affinity<<<T / 4, 256, 0, stream>>>(x, cent, bias, se, sw);
    k1b_partition<<<E, 256, 0, stream>>>(se, token_list, sp, cnt);
    k15_offsets<<<1, 64, 0, stream>>>(cnt, off, out + (size_t)T * H);
    k2_gateup<<<E * 32 * 32, 256, 0, stream>>>(xb, gwb, uwb, cnt, off, token_list, h);
    k_conv<<<(W4 + 255) / 256, 256, 0, stream>>>(dw, dwb, W4);  // aliases gwb; after k2
    k3_down<<<E * 32 * 8, 256, 0, stream>>>(h, dwb, cnt, off, y);  // y aliases uwb
    k_gather<<<T, 256, 0, stream>>>(y, se, sp, sw, off, out);
}

// Round 4
// 418.035 us; speedup vs baseline: 3.7979x; 1.0534x over previous
//
#include <hip/hip_runtime.h>
#include <math.h>

// Problem constants
constexpr int E = 8, H = 1024, DFF = 2048, T = 4096;
constexpr int TR = 8192;          // total routed rows = T * topk
constexpr int MAXJ = 72;          // max (expert, m-tile) jobs: 8192/128 + E

typedef __bf16 bf16x8 __attribute__((ext_vector_type(8)));
typedef __bf16 bf16x4 __attribute__((ext_vector_type(4)));
typedef float f32x4 __attribute__((ext_vector_type(4)));

__device__ __forceinline__ void gload16(const void* g, void* l) {
    __builtin_amdgcn_global_load_lds(
        (const __attribute__((address_space(1))) unsigned int*)g,
        (__attribute__((address_space(3))) unsigned int*)l, 16, 0, 0);
}

// ---------------- k1: affinity + top-2 (atomic-free) ----------------
__global__ __launch_bounds__(256) void k1_affinity(
    const float* __restrict__ x, const float* __restrict__ cent,
    const float* __restrict__ bias,
    int* __restrict__ se, float* __restrict__ sw) {
    __shared__ float cs[E * H];
    int tid = threadIdx.x;
    for (int i = tid; i < E * H / 4; i += 256)
        ((float4*)cs)[i] = ((const float4*)cent)[i];
    __syncthreads();

    int wave = tid >> 6, lane = tid & 63;
    int t = blockIdx.x * 4 + wave;
    const float4* xr = (const float4*)(x + (size_t)t * H);
    float acc[E] = {};
    #pragma unroll
    for (int it = 0; it < 4; it++) {
        float4 xv = xr[lane + it * 64];
        #pragma unroll
        for (int e = 0; e < E; e++) {
            float4 cv = ((const float4*)(cs + e * H))[lane + it * 64];
            acc[e] = fmaf(xv.x, cv.x, acc[e]);
            acc[e] = fmaf(xv.y, cv.y, acc[e]);
            acc[e] = fmaf(xv.z, cv.z, acc[e]);
            acc[e] = fmaf(xv.w, cv.w, acc[e]);
        }
    }
    #pragma unroll
    for (int off = 32; off; off >>= 1)
        #pragma unroll
        for (int e = 0; e < E; e++) acc[e] += __shfl_down(acc[e], off);

    if (lane == 0) {
        float s[E];
        #pragma unroll
        for (int e = 0; e < E; e++)
            s[e] = 1.0f / (1.0f + expf(-acc[e])) + bias[e];
        int i0 = 0;
        for (int e = 1; e < E; e++) if (s[e] > s[i0]) i0 = e;
        int i1 = -1;
        for (int e = 0; e < E; e++) {
            if (e == i0) continue;
            if (i1 < 0 || s[e] > s[i1]) i1 = e;
        }
        float m = fmaxf(s[i0], s[i1]);
        float w0 = expf(s[i0] - m), w1 = expf(s[i1] - m);
        float inv = 1.0f / (w0 + w1);
        se[2 * t] = i0;     sw[2 * t] = w0 * inv;
        se[2 * t + 1] = i1; sw[2 * t + 1] = w1 * inv;
    }
}

// ---------------- k1b: per-expert partition via block scan ----------------
__global__ __launch_bounds__(256) void k1b_partition(
    const int* __restrict__ se, int* __restrict__ token_list,
    int* __restrict__ sp, int* __restrict__ cnt) {
    int e = blockIdx.x;
    int tid = threadIdx.x;
    int wave = tid >> 6, lane = tid & 63;
    __shared__ int wsum[4];
    int running = 0;
    for (int c0 = 0; c0 < 2 * T; c0 += 256) {
        int i = c0 + tid;
        bool pred = (se[i] == e);
        unsigned long long mask = __ballot(pred);
        int pos_in_wave = __popcll(mask & ((1ull << lane) - 1ull));
        if (lane == 0) wsum[wave] = __popcll(mask);
        __syncthreads();
        int wbase = 0;
        for (int w2 = 0; w2 < wave; w2++) wbase += wsum[w2];
        int total = wsum[0] + wsum[1] + wsum[2] + wsum[3];
        if (pred) {
            int p = running + wbase + pos_in_wave;
            token_list[e * T + p] = i >> 1;
            sp[i] = p;
        }
        running += total;
        __syncthreads();
    }
    if (tid == 0) cnt[e] = running;
}

// ---------------- k1.5: offsets + counts output + job table ----------------
__global__ void k15_offsets(const int* __restrict__ cnt, int* __restrict__ off,
                            float* __restrict__ out_counts,
                            int* __restrict__ jobs, int* __restrict__ njobs) {
    if (threadIdx.x == 0) {
        int acc = 0, nj = 0;
        for (int e = 0; e < E; e++) {
            off[e] = acc; acc += cnt[e];
            int mts = (cnt[e] + 127) >> 7;
            for (int mt = 0; mt < mts; mt++) jobs[nj++] = e * 64 + mt;
        }
        njobs[0] = nj;
    }
    if (threadIdx.x < E) out_counts[threadIdx.x] = (float)cnt[threadIdx.x];
}

// ---------------- conv: fp32 -> bf16 (single tensor) ----------------
__global__ __launch_bounds__(256) void k_conv(const float* __restrict__ in,
                                              __bf16* __restrict__ out, int n4) {
    int i = blockIdx.x * 256 + threadIdx.x;
    if (i < n4) {
        float4 v = ((const float4*)in)[i];
        bf16x4 o = {(__bf16)v.x, (__bf16)v.y, (__bf16)v.z, (__bf16)v.w};
        ((bf16x4*)out)[i] = o;
    }
}

// ---------------- conv3: gw, uw, x in one launch ----------------
__global__ __launch_bounds__(256) void k_conv3(
    const float* __restrict__ gw, __bf16* __restrict__ gwb,
    const float* __restrict__ uw, __bf16* __restrict__ uwb,
    const float* __restrict__ x, __bf16* __restrict__ xb,
    int w4, int x4) {
    int i = blockIdx.x * 256 + threadIdx.x;
    const float* in; __bf16* out; int idx;
    if (i < w4) { in = gw; out = gwb; idx = i; }
    else if (i < 2 * w4) { in = uw; out = uwb; idx = i - w4; }
    else { idx = i - 2 * w4; if (idx >= x4) return; in = x; out = xb; }
    float4 v = ((const float4*)in)[idx];
    bf16x4 o = {(__bf16)v.x, (__bf16)v.y, (__bf16)v.z, (__bf16)v.w};
    ((bf16x4*)out)[idx] = o;
}

// ---------------- k2: grouped GEMM gate+up (MFMA), BK=64, fused SiLU*up ----------------
// Block tile 128m x 64n (dual gate/up). 4 waves, each 64x32 dual.
__global__ __launch_bounds__(256) void k2_gateup(
    const __bf16* __restrict__ xb, const __bf16* __restrict__ gwb,
    const __bf16* __restrict__ uwb, const int* __restrict__ cnt,
    const int* __restrict__ off, const int* __restrict__ token_list,
    const int* __restrict__ jobs, const int* __restrict__ njobs,
    __bf16* __restrict__ h) {
    int jt = blockIdx.x >> 5, nt = blockIdx.x & 31;
    if (jt >= njobs[0]) return;
    int job = jobs[jt];
    int e = job >> 6, mt = job & 63;
    int Me = cnt[e], offe = off[e];

    __shared__ __bf16 As[128 * 64];   // 16 KB
    __shared__ __bf16 Bg[64 * 64];    // 8 KB
    __shared__ __bf16 Bu[64 * 64];    // 8 KB

    int tid = threadIdx.x;
    int lane = tid & 63, w = tid >> 6;
    int wm = w >> 1, wn = w & 1;

    // staging sources: LDS slot (row, l&7) receives global k-chunk (l&7)^(row&7)
    const __bf16* asrc[4];
    #pragma unroll
    for (int rr = 0; rr < 4; rr++) {
        int l = rr * 256 + tid;
        int row = l >> 3, sl = l & 7;
        int gr = mt * 128 + row; if (gr >= Me) gr = Me - 1;
        int tok = token_list[e * T + gr];
        asrc[rr] = xb + (size_t)tok * H + ((sl ^ (row & 7)) * 8);
    }
    const __bf16 *bsg[2], *bsu[2];
    #pragma unroll
    for (int rr = 0; rr < 2; rr++) {
        int l = rr * 256 + tid;
        int row = l >> 3, sl = l & 7;
        size_t base = ((size_t)e * DFF + nt * 64 + row) * H + ((sl ^ (row & 7)) * 8);
        bsg[rr] = gwb + base;
        bsu[rr] = uwb + base;
    }

    f32x4 accg[4][2] = {};
    f32x4 accu[4][2] = {};
    int kq = lane >> 4, m15 = lane & 15;

    for (int k0 = 0; k0 < H; k0 += 64) {
        #pragma unroll
        for (int rr = 0; rr < 4; rr++)
            gload16(asrc[rr] + k0, &As[(rr * 256 + tid) * 8]);
        #pragma unroll
        for (int rr = 0; rr < 2; rr++) {
            gload16(bsg[rr] + k0, &Bg[(rr * 256 + tid) * 8]);
            gload16(bsu[rr] + k0, &Bu[(rr * 256 + tid) * 8]);
        }
        __syncthreads();

        #pragma unroll
        for (int kc = 0; kc < 2; kc++) {
            bf16x8 af[4], gf[2], uf[2];
            #pragma unroll
            for (int i = 0; i < 4; i++) {
                int row = wm * 64 + i * 16 + m15;
                int sl = (kc * 4 + kq) ^ (row & 7);
                af[i] = *(const bf16x8*)&As[row * 64 + sl * 8];
            }
            #pragma unroll
            for (int j = 0; j < 2; j++) {
                int row = wn * 32 + j * 16 + m15;
                int sl = (kc * 4 + kq) ^ (row & 7);
                gf[j] = *(const bf16x8*)&Bg[row * 64 + sl * 8];
                uf[j] = *(const bf16x8*)&Bu[row * 64 + sl * 8];
            }
            #pragma unroll
            for (int i = 0; i < 4; i++)
                #pragma unroll
                for (int j = 0; j < 2; j++) {
                    accg[i][j] = __builtin_amdgcn_mfma_f32_16x16x32_bf16(af[i], gf[j], accg[i][j], 0, 0, 0);
                    accu[i][j] = __builtin_amdgcn_mfma_f32_16x16x32_bf16(af[i], uf[j], accu[i][j], 0, 0, 0);
                }
        }
        __syncthreads();
    }

    // epilogue: h = silu(g) * u
    #pragma unroll
    for (int i = 0; i < 4; i++)
        #pragma unroll
        for (int j = 0; j < 2; j++) {
            int nloc = wn * 32 + j * 16 + m15;
            size_t c = (size_t)nt * 64 + nloc;
            #pragma unroll
            for (int p = 0; p < 4; p++) {
                int mloc = wm * 64 + i * 16 + kq * 4 + p;
                int mrow = mt * 128 + mloc;
                if (mrow < Me) {
                    float g = accg[i][j][p], u = accu[i][j][p];
                    float sig = 1.0f / (1.0f + __expf(-g));
                    h[(size_t)(offe + mrow) * DFF + c] = (__bf16)(g * sig * u);
                }
            }
        }
}

// ---------------- k3: grouped GEMM down (MFMA), BK=64 -> per-row y ----------------
// Block tile 128m x 128n. 4 waves 2x2, each 64x64.
__global__ __launch_bounds__(256) void k3_down(
    const __bf16* __restrict__ h, const __bf16* __restrict__ dwb,
    const int* __restrict__ cnt, const int* __restrict__ off,
    const int* __restrict__ jobs, const int* __restrict__ njobs,
    __bf16* __restrict__ y) {
    int jt = blockIdx.x >> 3, nt = blockIdx.x & 7;
    if (jt >= njobs[0]) return;
    int job = jobs[jt];
    int e = job >> 6, mt = job & 63;
    int Me = cnt[e], offe = off[e];

    __shared__ __bf16 As[128 * 64];   // 16 KB
    __shared__ __bf16 Bs[128 * 64];   // 16 KB

    int tid = threadIdx.x;
    int lane = tid & 63, w = tid >> 6;
    int wm = w >> 1, wn = w & 1;

    const __bf16 *asrc[4], *bsrc[4];
    #pragma unroll
    for (int rr = 0; rr < 4; rr++) {
        int l = rr * 256 + tid;
        int row = l >> 3, sl = l & 7;
        int koff = (sl ^ (row & 7)) * 8;
        int gr = mt * 128 + row; if (gr >= Me) gr = Me - 1;
        asrc[rr] = h + (size_t)(offe + gr) * DFF + koff;
        bsrc[rr] = dwb + ((size_t)e * H + nt * 128 + row) * DFF + koff;
    }

    f32x4 acc[4][4] = {};
    int kq = lane >> 4, m15 = lane & 15;

    for (int k0 = 0; k0 < DFF; k0 += 64) {
        #pragma unroll
        for (int rr = 0; rr < 4; rr++) {
            gload16(asrc[rr] + k0, &As[(rr * 256 + tid) * 8]);
            gload16(bsrc[rr] + k0, &Bs[(rr * 256 + tid) * 8]);
        }
        __syncthreads();

        #pragma unroll
        for (int kc = 0; kc < 2; kc++) {
            bf16x8 af[4], bf[4];
            #pragma unroll
            for (int i = 0; i < 4; i++) {
                int row = wm * 64 + i * 16 + m15;
                int sl = (kc * 4 + kq) ^ (row & 7);
                af[i] = *(const bf16x8*)&As[row * 64 + sl * 8];
            }
            #pragma unroll
            for (int j = 0; j < 4; j++) {
                int row = wn * 64 + j * 16 + m15;
                int sl = (kc * 4 + kq) ^ (row & 7);
                bf[j] = *(const bf16x8*)&Bs[row * 64 + sl * 8];
            }
            #pragma unroll
            for (int i = 0; i < 4; i++)
                #pragma unroll
                for (int j = 0; j < 4; j++)
                    acc[i][j] = __builtin_amdgcn_mfma_f32_16x16x32_bf16(af[i], bf[j], acc[i][j], 0, 0, 0);
        }
        __syncthreads();
    }

    #pragma unroll
    for (int i = 0; i < 4; i++)
        #pragma unroll
        for (int j = 0; j < 4; j++) {
            int nglob = nt * 128 + wn * 64 + j * 16 + m15;
            #pragma unroll
            for (int p = 0; p < 4; p++) {
                int mloc = wm * 64 + i * 16 + kq * 4 + p;
                int mrow = mt * 128 + mloc;
                if (mrow < Me)
                    y[(size_t)(offe + mrow) * H + nglob] = (__bf16)acc[i][j][p];
            }
        }
}

// ---------------- gather: weighted top-2 combine -> out ----------------
__global__ __launch_bounds__(256) void k_gather(
    const __bf16* __restrict__ y, const int* __restrict__ se,
    const int* __restrict__ sp, const float* __restrict__ sw,
    const int* __restrict__ off, float* __restrict__ out) {
    int t = blockIdx.x;
    int r0 = off[se[2 * t]] + sp[2 * t];
    int r1 = off[se[2 * t + 1]] + sp[2 * t + 1];
    float w0 = sw[2 * t], w1 = sw[2 * t + 1];
    const bf16x4* y0 = (const bf16x4*)(y + (size_t)r0 * H);
    const bf16x4* y1 = (const bf16x4*)(y + (size_t)r1 * H);
    float4* o = (float4*)(out + (size_t)t * H);
    int c = threadIdx.x;
    bf16x4 a = y0[c], b = y1[c];
    float4 v;
    v.x = w0 * (float)a[0] + w1 * (float)b[0];
    v.y = w0 * (float)a[1] + w1 * (float)b[1];
    v.z = w0 * (float)a[2] + w1 * (float)b[2];
    v.w = w0 * (float)a[3] + w1 * (float)b[3];
    o[c] = v;
}

// ---------------- launch ----------------
extern "C" void kernel_launch(void* const* d_in, const int* in_sizes, int n_in,
                              void* d_out, int out_size, void* d_ws, size_t ws_size,
                              hipStream_t stream) {
    const float* x    = (const float*)d_in[0];
    const float* cent = (const float*)d_in[1];
    const float* gw   = (const float*)d_in[2];
    const float* uw   = (const float*)d_in[3];
    const float* dw   = (const float*)d_in[4];
    const float* bias = (const float*)d_in[5];
    float* out = (float*)d_out;

    // workspace layout (bytes)
    char* ws = (char*)d_ws;
    int*   cnt        = (int*)(ws + 0);
    int*   off        = (int*)(ws + 64);
    int*   se         = (int*)(ws + 128);              // 32 KB
    int*   sp         = (int*)(ws + 128 + 32768);      // 32 KB
    float* sw         = (float*)(ws + 128 + 65536);    // 32 KB
    int*   token_list = (int*)(ws + 128 + 98304);      // 128 KB
    int*   jobs       = (int*)(ws + 229504);           // 80 ints
    int*   njobs      = (int*)(ws + 229824);           // 1 int
    const size_t MB = 1u << 20;
    __bf16* gwb = (__bf16*)(ws + 1 * MB);              // 32 MB
    __bf16* uwb = (__bf16*)(ws + 1 * MB + 33554432);   // 32 MB
    __bf16* dwb = gwb;                                 // alias: after k2
    __bf16* y   = uwb;                                 // alias: uwb dead after k2
    __bf16* xb  = (__bf16*)(ws + 1 * MB + 67108864);   // 8 MB
    __bf16* h   = (__bf16*)(ws + 1 * MB + 75497472);   // 32 MB

    const int W4 = E * DFF * H / 4;
    const int X4 = T * H / 4;
    const int C3 = 2 * W4 + X4;

    k_conv3<<<(C3 + 255) / 256, 256, 0, stream>>>(gw, gwb, uw, uwb, x, xb, W4, X4);
    k1_affinity<<<T / 4, 256, 0, stream>>>(x, cent, bias, se, sw);
    k1b_partition<<<E, 256, 0, stream>>>(se, token_list, sp, cnt);
    k15_offsets<<<1, 64, 0, stream>>>(cnt, off, out + (size_t)T * H, jobs, njobs);
    k2_gateup<<<MAXJ * 32, 256, 0, stream>>>(xb, gwb, uwb, cnt, off, token_list, jobs, njobs, h);
    k_conv<<<(W4 + 255) / 256, 256, 0, stream>>>(dw, dwb, W4);  // aliases gwb; after k2
    k3_down<<<MAXJ * 8, 256, 0, stream>>>(h, dwb, cnt, off, jobs, njobs, y);  // y aliases uwb
    k_gather<<<T, 256, 0, stream>>>(y, se, sp, sw, off, out);
}

// Round 5
// 389.441 us; speedup vs baseline: 4.0768x; 1.0734x over previous
//
#include <hip/hip_runtime.h>
#include <math.h>

// Problem constants
constexpr int E = 8, H = 1024, DFF = 2048, T = 4096;
constexpr int TR = 8192;          // total routed rows = T * topk
constexpr int MAXJ = 72;          // max (expert, m-tile) jobs: 8192/128 + E

typedef __bf16 bf16x8 __attribute__((ext_vector_type(8)));
typedef __bf16 bf16x4 __attribute__((ext_vector_type(4)));
typedef float f32x4 __attribute__((ext_vector_type(4)));

__device__ __forceinline__ void gload16(const void* g, void* l) {
    __builtin_amdgcn_global_load_lds(
        (const __attribute__((address_space(1))) unsigned int*)g,
        (__attribute__((address_space(3))) unsigned int*)l, 16, 0, 0);
}

// ---------------- k1: affinity + top-2 (atomic-free) ----------------
__global__ __launch_bounds__(256) void k1_affinity(
    const float* __restrict__ x, const float* __restrict__ cent,
    const float* __restrict__ bias,
    int* __restrict__ se, float* __restrict__ sw) {
    __shared__ float cs[E * H];
    int tid = threadIdx.x;
    for (int i = tid; i < E * H / 4; i += 256)
        ((float4*)cs)[i] = ((const float4*)cent)[i];
    __syncthreads();

    int wave = tid >> 6, lane = tid & 63;
    int t = blockIdx.x * 4 + wave;
    const float4* xr = (const float4*)(x + (size_t)t * H);
    float acc[E] = {};
    #pragma unroll
    for (int it = 0; it < 4; it++) {
        float4 xv = xr[lane + it * 64];
        #pragma unroll
        for (int e = 0; e < E; e++) {
            float4 cv = ((const float4*)(cs + e * H))[lane + it * 64];
            acc[e] = fmaf(xv.x, cv.x, acc[e]);
            acc[e] = fmaf(xv.y, cv.y, acc[e]);
            acc[e] = fmaf(xv.z, cv.z, acc[e]);
            acc[e] = fmaf(xv.w, cv.w, acc[e]);
        }
    }
    #pragma unroll
    for (int off = 32; off; off >>= 1)
        #pragma unroll
        for (int e = 0; e < E; e++) acc[e] += __shfl_down(acc[e], off);

    if (lane == 0) {
        float s[E];
        #pragma unroll
        for (int e = 0; e < E; e++)
            s[e] = 1.0f / (1.0f + expf(-acc[e])) + bias[e];
        int i0 = 0;
        for (int e = 1; e < E; e++) if (s[e] > s[i0]) i0 = e;
        int i1 = -1;
        for (int e = 0; e < E; e++) {
            if (e == i0) continue;
            if (i1 < 0 || s[e] > s[i1]) i1 = e;
        }
        float m = fmaxf(s[i0], s[i1]);
        float w0 = expf(s[i0] - m), w1 = expf(s[i1] - m);
        float inv = 1.0f / (w0 + w1);
        se[2 * t] = i0;     sw[2 * t] = w0 * inv;
        se[2 * t + 1] = i1; sw[2 * t + 1] = w1 * inv;
    }
}

// ---------------- k1b: per-expert partition via block scan ----------------
__global__ __launch_bounds__(256) void k1b_partition(
    const int* __restrict__ se, int* __restrict__ token_list,
    int* __restrict__ sp, int* __restrict__ cnt) {
    int e = blockIdx.x;
    int tid = threadIdx.x;
    int wave = tid >> 6, lane = tid & 63;
    __shared__ int wsum[4];
    int running = 0;
    for (int c0 = 0; c0 < 2 * T; c0 += 256) {
        int i = c0 + tid;
        bool pred = (se[i] == e);
        unsigned long long mask = __ballot(pred);
        int pos_in_wave = __popcll(mask & ((1ull << lane) - 1ull));
        if (lane == 0) wsum[wave] = __popcll(mask);
        __syncthreads();
        int wbase = 0;
        for (int w2 = 0; w2 < wave; w2++) wbase += wsum[w2];
        int total = wsum[0] + wsum[1] + wsum[2] + wsum[3];
        if (pred) {
            int p = running + wbase + pos_in_wave;
            token_list[e * T + p] = i >> 1;
            sp[i] = p;
        }
        running += total;
        __syncthreads();
    }
    if (tid == 0) cnt[e] = running;
}

// ---------------- k1.5: offsets + counts output + job table ----------------
__global__ void k15_offsets(const int* __restrict__ cnt, int* __restrict__ off,
                            float* __restrict__ out_counts,
                            int* __restrict__ jobs, int* __restrict__ njobs) {
    if (threadIdx.x == 0) {
        int acc = 0, nj = 0;
        for (int e = 0; e < E; e++) {
            off[e] = acc; acc += cnt[e];
            int mts = (cnt[e] + 127) >> 7;
            for (int mt = 0; mt < mts; mt++) jobs[nj++] = e * 64 + mt;
        }
        njobs[0] = nj;
    }
    if (threadIdx.x < E) out_counts[threadIdx.x] = (float)cnt[threadIdx.x];
}

// ---------------- conv: fp32 -> bf16 (single tensor) ----------------
__global__ __launch_bounds__(256) void k_conv(const float* __restrict__ in,
                                              __bf16* __restrict__ out, int n4) {
    int i = blockIdx.x * 256 + threadIdx.x;
    if (i < n4) {
        float4 v = ((const float4*)in)[i];
        bf16x4 o = {(__bf16)v.x, (__bf16)v.y, (__bf16)v.z, (__bf16)v.w};
        ((bf16x4*)out)[i] = o;
    }
}

// ---------------- conv3: gw, uw, x in one launch ----------------
__global__ __launch_bounds__(256) void k_conv3(
    const float* __restrict__ gw, __bf16* __restrict__ gwb,
    const float* __restrict__ uw, __bf16* __restrict__ uwb,
    const float* __restrict__ x, __bf16* __restrict__ xb,
    int w4, int x4) {
    int i = blockIdx.x * 256 + threadIdx.x;
    const float* in; __bf16* out; int idx;
    if (i < w4) { in = gw; out = gwb; idx = i; }
    else if (i < 2 * w4) { in = uw; out = uwb; idx = i - w4; }
    else { idx = i - 2 * w4; if (idx >= x4) return; in = x; out = xb; }
    float4 v = ((const float4*)in)[idx];
    bf16x4 o = {(__bf16)v.x, (__bf16)v.y, (__bf16)v.z, (__bf16)v.w};
    ((bf16x4*)out)[idx] = o;
}

// ---------------- k2: grouped GEMM gate+up (MFMA), BK=64, tile 128x128 dual ----------------
// 4 waves 2x2; each wave owns a 64x64 region of BOTH gate and up accumulators.
__global__ __launch_bounds__(256, 2) void k2_gateup(
    const __bf16* __restrict__ xb, const __bf16* __restrict__ gwb,
    const __bf16* __restrict__ uwb, const int* __restrict__ cnt,
    const int* __restrict__ off, const int* __restrict__ token_list,
    const int* __restrict__ jobs, const int* __restrict__ njobs,
    __bf16* __restrict__ h) {
    int jt = blockIdx.x >> 4, nt = blockIdx.x & 15;   // nt: 0..15 (DFF/128)
    if (jt >= njobs[0]) return;
    int job = jobs[jt];
    int e = job >> 6, mt = job & 63;
    int Me = cnt[e], offe = off[e];

    __shared__ __bf16 As[128 * 64];   // 16 KB
    __shared__ __bf16 Bg[128 * 64];   // 16 KB
    __shared__ __bf16 Bu[128 * 64];   // 16 KB

    int tid = threadIdx.x;
    int lane = tid & 63, w = tid >> 6;
    int wm = w >> 1, wn = w & 1;

    // staging sources: LDS slot (row, l&7) receives global k-chunk (l&7)^(row&7)
    const __bf16* asrc[4];
    const __bf16 *bsg[4], *bsu[4];
    #pragma unroll
    for (int rr = 0; rr < 4; rr++) {
        int l = rr * 256 + tid;
        int row = l >> 3, sl = l & 7;
        int gr = mt * 128 + row; if (gr >= Me) gr = Me - 1;
        int tok = token_list[e * T + gr];
        asrc[rr] = xb + (size_t)tok * H + ((sl ^ (row & 7)) * 8);
        size_t base = ((size_t)e * DFF + nt * 128 + row) * H + ((sl ^ (row & 7)) * 8);
        bsg[rr] = gwb + base;
        bsu[rr] = uwb + base;
    }

    f32x4 accg[4][4] = {};
    f32x4 accu[4][4] = {};
    int kq = lane >> 4, m15 = lane & 15;

    for (int k0 = 0; k0 < H; k0 += 64) {
        #pragma unroll
        for (int rr = 0; rr < 4; rr++) {
            gload16(asrc[rr] + k0, &As[(rr * 256 + tid) * 8]);
            gload16(bsg[rr] + k0, &Bg[(rr * 256 + tid) * 8]);
            gload16(bsu[rr] + k0, &Bu[(rr * 256 + tid) * 8]);
        }
        __syncthreads();

        #pragma unroll
        for (int kc = 0; kc < 2; kc++) {
            bf16x8 af[4], gf[4], uf[4];
            #pragma unroll
            for (int i = 0; i < 4; i++) {
                int row = wm * 64 + i * 16 + m15;
                int sl = (kc * 4 + kq) ^ (row & 7);
                af[i] = *(const bf16x8*)&As[row * 64 + sl * 8];
            }
            #pragma unroll
            for (int j = 0; j < 4; j++) {
                int row = wn * 64 + j * 16 + m15;
                int sl = (kc * 4 + kq) ^ (row & 7);
                gf[j] = *(const bf16x8*)&Bg[row * 64 + sl * 8];
                uf[j] = *(const bf16x8*)&Bu[row * 64 + sl * 8];
            }
            #pragma unroll
            for (int i = 0; i < 4; i++)
                #pragma unroll
                for (int j = 0; j < 4; j++) {
                    accg[i][j] = __builtin_amdgcn_mfma_f32_16x16x32_bf16(af[i], gf[j], accg[i][j], 0, 0, 0);
                    accu[i][j] = __builtin_amdgcn_mfma_f32_16x16x32_bf16(af[i], uf[j], accu[i][j], 0, 0, 0);
                }
        }
        __syncthreads();
    }

    // epilogue: h = silu(g) * u
    #pragma unroll
    for (int i = 0; i < 4; i++)
        #pragma unroll
        for (int j = 0; j < 4; j++) {
            int nloc = wn * 64 + j * 16 + m15;
            size_t c = (size_t)nt * 128 + nloc;
            #pragma unroll
            for (int p = 0; p < 4; p++) {
                int mloc = wm * 64 + i * 16 + kq * 4 + p;
                int mrow = mt * 128 + mloc;
                if (mrow < Me) {
                    float g = accg[i][j][p], u = accu[i][j][p];
                    float sig = 1.0f / (1.0f + __expf(-g));
                    h[(size_t)(offe + mrow) * DFF + c] = (__bf16)(g * sig * u);
                }
            }
        }
}

// ---------------- k3: grouped GEMM down (MFMA), BK=64, tile 128x256 ----------------
// 512 threads, 8 waves (2m x 4n); each wave owns a 64x64 region.
__global__ __launch_bounds__(512, 2) void k3_down(
    const __bf16* __restrict__ h, const __bf16* __restrict__ dwb,
    const int* __restrict__ cnt, const int* __restrict__ off,
    const int* __restrict__ jobs, const int* __restrict__ njobs,
    __bf16* __restrict__ y) {
    int jt = blockIdx.x >> 2, nt = blockIdx.x & 3;    // nt: 0..3 (H/256)
    if (jt >= njobs[0]) return;
    int job = jobs[jt];
    int e = job >> 6, mt = job & 63;
    int Me = cnt[e], offe = off[e];

    __shared__ __bf16 As[128 * 64];   // 16 KB
    __shared__ __bf16 Bs[256 * 64];   // 32 KB

    int tid = threadIdx.x;
    int lane = tid & 63, w = tid >> 6;
    int wm = w >> 2, wn = w & 3;

    const __bf16* asrc[2];
    #pragma unroll
    for (int rr = 0; rr < 2; rr++) {
        int l = rr * 512 + tid;
        int row = l >> 3, sl = l & 7;
        int koff = (sl ^ (row & 7)) * 8;
        int gr = mt * 128 + row; if (gr >= Me) gr = Me - 1;
        asrc[rr] = h + (size_t)(offe + gr) * DFF + koff;
    }
    const __bf16* bsrc[4];
    #pragma unroll
    for (int rr = 0; rr < 4; rr++) {
        int l = rr * 512 + tid;
        int row = l >> 3, sl = l & 7;
        int koff = (sl ^ (row & 7)) * 8;
        bsrc[rr] = dwb + ((size_t)e * H + nt * 256 + row) * DFF + koff;
    }

    f32x4 acc[4][4] = {};
    int kq = lane >> 4, m15 = lane & 15;

    for (int k0 = 0; k0 < DFF; k0 += 64) {
        #pragma unroll
        for (int rr = 0; rr < 2; rr++)
            gload16(asrc[rr] + k0, &As[(rr * 512 + tid) * 8]);
        #pragma unroll
        for (int rr = 0; rr < 4; rr++)
            gload16(bsrc[rr] + k0, &Bs[(rr * 512 + tid) * 8]);
        __syncthreads();

        #pragma unroll
        for (int kc = 0; kc < 2; kc++) {
            bf16x8 af[4], bf[4];
            #pragma unroll
            for (int i = 0; i < 4; i++) {
                int row = wm * 64 + i * 16 + m15;
                int sl = (kc * 4 + kq) ^ (row & 7);
                af[i] = *(const bf16x8*)&As[row * 64 + sl * 8];
            }
            #pragma unroll
            for (int j = 0; j < 4; j++) {
                int row = wn * 64 + j * 16 + m15;
                int sl = (kc * 4 + kq) ^ (row & 7);
                bf[j] = *(const bf16x8*)&Bs[row * 64 + sl * 8];
            }
            #pragma unroll
            for (int i = 0; i < 4; i++)
                #pragma unroll
                for (int j = 0; j < 4; j++)
                    acc[i][j] = __builtin_amdgcn_mfma_f32_16x16x32_bf16(af[i], bf[j], acc[i][j], 0, 0, 0);
        }
        __syncthreads();
    }

    #pragma unroll
    for (int i = 0; i < 4; i++)
        #pragma unroll
        for (int j = 0; j < 4; j++) {
            int nglob = nt * 256 + wn * 64 + j * 16 + m15;
            #pragma unroll
            for (int p = 0; p < 4; p++) {
                int mloc = wm * 64 + i * 16 + kq * 4 + p;
                int mrow = mt * 128 + mloc;
                if (mrow < Me)
                    y[(size_t)(offe + mrow) * H + nglob] = (__bf16)acc[i][j][p];
            }
        }
}

// ---------------- gather: weighted top-2 combine -> out ----------------
__global__ __launch_bounds__(256) void k_gather(
    const __bf16* __restrict__ y, const int* __restrict__ se,
    const int* __restrict__ sp, const float* __restrict__ sw,
    const int* __restrict__ off, float* __restrict__ out) {
    int t = blockIdx.x;
    int r0 = off[se[2 * t]] + sp[2 * t];
    int r1 = off[se[2 * t + 1]] + sp[2 * t + 1];
    float w0 = sw[2 * t], w1 = sw[2 * t + 1];
    const bf16x4* y0 = (const bf16x4*)(y + (size_t)r0 * H);
    const bf16x4* y1 = (const bf16x4*)(y + (size_t)r1 * H);
    float4* o = (float4*)(out + (size_t)t * H);
    int c = threadIdx.x;
    bf16x4 a = y0[c], b = y1[c];
    float4 v;
    v.x = w0 * (float)a[0] + w1 * (float)b[0];
    v.y = w0 * (float)a[1] + w1 * (float)b[1];
    v.z = w0 * (float)a[2] + w1 * (float)b[2];
    v.w = w0 * (float)a[3] + w1 * (float)b[3];
    o[c] = v;
}

// ---------------- launch ----------------
extern "C" void kernel_launch(void* const* d_in, const int* in_sizes, int n_in,
                              void* d_out, int out_size, void* d_ws, size_t ws_size,
                              hipStream_t stream) {
    const float* x    = (const float*)d_in[0];
    const float* cent = (const float*)d_in[1];
    const float* gw   = (const float*)d_in[2];
    const float* uw   = (const float*)d_in[3];
    const float* dw   = (const float*)d_in[4];
    const float* bias = (const float*)d_in[5];
    float* out = (float*)d_out;

    // workspace layout (bytes)
    char* ws = (char*)d_ws;
    int*   cnt        = (int*)(ws + 0);
    int*   off        = (int*)(ws + 64);
    int*   se         = (int*)(ws + 128);              // 32 KB
    int*   sp         = (int*)(ws + 128 + 32768);      // 32 KB
    float* sw         = (float*)(ws + 128 + 65536);    // 32 KB
    int*   token_list = (int*)(ws + 128 + 98304);      // 128 KB
    int*   jobs       = (int*)(ws + 229504);           // 80 ints
    int*   njobs      = (int*)(ws + 229824);           // 1 int
    const size_t MB = 1u << 20;
    __bf16* gwb = (__bf16*)(ws + 1 * MB);              // 32 MB
    __bf16* uwb = (__bf16*)(ws + 1 * MB + 33554432);   // 32 MB
    __bf16* dwb = gwb;                                 // alias: after k2
    __bf16* y   = uwb;                                 // alias: uwb dead after k2
    __bf16* xb  = (__bf16*)(ws + 1 * MB + 67108864);   // 8 MB
    __bf16* h   = (__bf16*)(ws + 1 * MB + 75497472);   // 32 MB

    const int W4 = E * DFF * H / 4;
    const int X4 = T * H / 4;
    const int C3 = 2 * W4 + X4;

    k_conv3<<<(C3 + 255) / 256, 256, 0, stream>>>(gw, gwb, uw, uwb, x, xb, W4, X4);
    k1_affinity<<<T / 4, 256, 0, stream>>>(x, cent, bias, se, sw);
    k1b_partition<<<E, 256, 0, stream>>>(se, token_list, sp, cnt);
    k15_offsets<<<1, 64, 0, stream>>>(cnt, off, out + (size_t)T * H, jobs, njobs);
    k2_gateup<<<MAXJ * 16, 256, 0, stream>>>(xb, gwb, uwb, cnt, off, token_list, jobs, njobs, h);
    k_conv<<<(W4 + 255) / 256, 256, 0, stream>>>(dw, dwb, W4);  // aliases gwb; after k2
    k3_down<<<MAXJ * 4, 512, 0, stream>>>(h, dwb, cnt, off, jobs, njobs, y);  // y aliases uwb
    k_gather<<<T, 256, 0, stream>>>(y, se, sp, sw, off, out);
}